// Round 8
// baseline (203.584 us; speedup 1.0000x reference)
//
#include <hip/hip_runtime.h>
#include <hip/hip_bf16.h>

// ViT embed: patchify + linear + cls + posemb + LayerNorm, fused.
// images [128,3,224,224] f32 -> out [128,197,768] f32.
// M = 128*196 = 25088 patch-rows, K = 768, N = 768.
// v8: OCCUPANCY, not ILP. All 7 prior rounds sat at ~17% occupancy because
// acc(96 AGPR)+~128 arch VGPR = 224 regs/wave -> 2 waves/SIMD cap (m69
// thresholds 64/128/256 on the unified file). Halve the wave tile to
// 32x96 (acc=48 AGPR), strip the K-loop to pure dataflow (no LDS, no
// barriers, no asm; direct global A-frags + in-reg cvt, B single-buffered
// imm-offset loads), and cap total regs <=128 via __launch_bounds__(512,4)
// -> 4 waves/SIMD = 16 waves/CU. 6272 free-running waves hide latency by
// TLP. B L2 traffic doubles to ~924MB (acceptable: latency-hideable).

#define IMG_B 128
#define IMG_C 3
#define IMG_HW 224
#define DTOK 768
#define NTOK 197
#define MROWS 25088

typedef __attribute__((ext_vector_type(4))) float f32x4;
typedef __attribute__((ext_vector_type(8))) short bf16x8;

__device__ __forceinline__ unsigned short f2b(float f) {
  union { float f; unsigned u; } v; v.f = f;
  unsigned u = v.u;
  return (unsigned short)((u + 0x7fffu + ((u >> 16) & 1u)) >> 16);
}

// ---------------- setup kernels ----------------

__global__ void conv_w(const float* __restrict__ W, unsigned short* __restrict__ Wb) {
  int i = blockIdx.x * 256 + threadIdx.x;
  if (i < DTOK * DTOK) Wb[i] = f2b(W[i]);
}

__global__ void make_bpos(const float* __restrict__ bias, const float* __restrict__ cls,
                          float* __restrict__ bpos) {
  int i = blockIdx.x * 256 + threadIdx.x;
  if (i >= NTOK * DTOK) return;
  int t = i / DTOK, d = i - (i / DTOK) * DTOK;
  float expo = (float)(d & ~1) * (1.0f / (float)DTOK);
  float angle = (float)t * exp2f(-expo * 13.287712379549449f);
  float pv = (d & 1) ? cosf(angle) : sinf(angle);
  bpos[i] = pv + ((t == 0) ? cls[d] : bias[d]);
}

__global__ __launch_bounds__(256) void cls_kernel(const float* __restrict__ bpos,
                                                  const float* __restrict__ gamma,
                                                  const float* __restrict__ beta,
                                                  float* __restrict__ out) {
  __shared__ float sred[8];
  const int tid = threadIdx.x;
  float v0 = bpos[tid], v1 = bpos[tid + 256], v2 = bpos[tid + 512];
  float s1 = v0 + v1 + v2;
  float s2 = v0 * v0 + v1 * v1 + v2 * v2;
  #pragma unroll
  for (int off = 32; off >= 1; off >>= 1) {
    s1 += __shfl_xor(s1, off, 64);
    s2 += __shfl_xor(s2, off, 64);
  }
  if ((tid & 63) == 0) { sred[(tid >> 6) * 2] = s1; sred[(tid >> 6) * 2 + 1] = s2; }
  __syncthreads();
  float S1 = sred[0] + sred[2] + sred[4] + sred[6];
  float S2 = sred[1] + sred[3] + sred[5] + sred[7];
  float mean = S1 * (1.0f / 768.0f);
  float rstd = rsqrtf(S2 * (1.0f / 768.0f) - mean * mean + 1e-5f);
  float o0 = (v0 - mean) * rstd * gamma[tid] + beta[tid];
  float o1 = (v1 - mean) * rstd * gamma[tid + 256] + beta[tid + 256];
  float o2 = (v2 - mean) * rstd * gamma[tid + 512] + beta[tid + 512];
  for (int b = 0; b < IMG_B; ++b) {
    float* op = out + (size_t)b * NTOK * DTOK;
    op[tid] = o0; op[tid + 256] = o1; op[tid + 512] = o2;
  }
}

// ---------------- main fused kernel ----------------
// 512 thr / 8 waves. Block = 32 rows x 768 cols; wave = 32 rows x 96 cols
// (2 mf x 6 nf, acc = 48 regs). K-loop: barrier-free pure dataflow.

__global__ __launch_bounds__(512, 4) void vit_main(
    const float* __restrict__ images, const unsigned short* __restrict__ Wb,
    const float* __restrict__ bpos, const float* __restrict__ gamma,
    const float* __restrict__ beta, float* __restrict__ out) {
  __shared__ float red[8][32][2];
  __shared__ float rowstat[32][2];

  const int tid = threadIdx.x;
  const int wid = tid >> 6;       // n-slice 0..7
  const int lane = tid & 63;
  const int l15 = lane & 15;
  const int g = lane >> 4;
  const int blk = blockIdx.x;
  const int cbase = wid * 96;

  // A row base pointers (mf = 0,1): row m = blk*32 + mf*16 + l15.
  // Lane covers k = g*8..g*8+7 -> fold pw = (g&1)*8 into the base; per-step
  // offset: idx = it*2 + (g>>1); aoff = (idx>>4)*50176 + (idx&15)*224.
  const float* abase[2];
  #pragma unroll
  for (int mf = 0; mf < 2; ++mf) {
    const int m = blk * 32 + mf * 16 + l15;
    const int sb = m / 196;
    const int sp = m - sb * 196;
    const int spy = sp / 14, spx = sp - (sp / 14) * 14;
    abase[mf] = images + (size_t)sb * (IMG_C * IMG_HW * IMG_HW) +
                (spy * 16) * IMG_HW + spx * 16 + (g & 1) * 8;
  }
  const int gb = g >> 1;

  // B per-lane base per nf; step it adds it*32 ushorts = it*64 B (imm-folded)
  const unsigned short* bbase[6];
  #pragma unroll
  for (int nf = 0; nf < 6; ++nf)
    bbase[nf] = Wb + (size_t)(cbase + nf * 16 + l15) * DTOK + g * 8;

  f32x4 acc[2][6];
  #pragma unroll
  for (int mf = 0; mf < 2; ++mf)
    #pragma unroll
    for (int nf = 0; nf < 6; ++nf)
      acc[mf][nf] = (f32x4)(0.0f);

  #pragma unroll
  for (int it = 0; it < 24; ++it) {
    const int idx = it * 2 + gb;
    const int aoff = (idx >> 4) * (IMG_HW * IMG_HW) + (idx & 15) * IMG_HW;

    bf16x8 afr[2];
    #pragma unroll
    for (int mf = 0; mf < 2; ++mf) {
      const float4 v0 = *(const float4*)(abase[mf] + aoff);
      const float4 v1 = *(const float4*)(abase[mf] + aoff + 4);
      union { __hip_bfloat162 h2[4]; bf16x8 v; } u;
      u.h2[0] = __float22bfloat162_rn(make_float2(v0.x, v0.y));
      u.h2[1] = __float22bfloat162_rn(make_float2(v0.z, v0.w));
      u.h2[2] = __float22bfloat162_rn(make_float2(v1.x, v1.y));
      u.h2[3] = __float22bfloat162_rn(make_float2(v1.z, v1.w));
      afr[mf] = u.v;
    }

    #pragma unroll
    for (int nf = 0; nf < 6; ++nf) {
      const bf16x8 bf = *(const bf16x8*)(bbase[nf] + it * 32);
      acc[0][nf] = __builtin_amdgcn_mfma_f32_16x16x32_bf16(afr[0], bf, acc[0][nf], 0, 0, 0);
      acc[1][nf] = __builtin_amdgcn_mfma_f32_16x16x32_bf16(afr[1], bf, acc[1][nf], 0, 0, 0);
    }
  }

  // ---- epilogue: +bias+pos, row LN over full 768 ----
  float s1[8], s2[8];
  #pragma unroll
  for (int mf = 0; mf < 2; ++mf) {
    #pragma unroll
    for (int r = 0; r < 4; ++r) {
      const int rl = mf * 16 + g * 4 + r;
      const int m = blk * 32 + rl;
      const int trow = 1 + (m % 196);
      const float* bp = bpos + (size_t)trow * DTOK + cbase + l15;
      float a1 = 0.f, a2 = 0.f;
      #pragma unroll
      for (int nf = 0; nf < 6; ++nf) {
        float val = acc[mf][nf][r] + bp[nf * 16];
        acc[mf][nf][r] = val;
        a1 += val; a2 += val * val;
      }
      s1[mf * 4 + r] = a1; s2[mf * 4 + r] = a2;
    }
  }
  #pragma unroll
  for (int off = 8; off >= 1; off >>= 1) {
    #pragma unroll
    for (int i = 0; i < 8; ++i) {
      s1[i] += __shfl_xor(s1[i], off, 64);
      s2[i] += __shfl_xor(s2[i], off, 64);
    }
  }
  if (l15 == 0) {
    #pragma unroll
    for (int mf = 0; mf < 2; ++mf)
      #pragma unroll
      for (int r = 0; r < 4; ++r) {
        const int rl = mf * 16 + g * 4 + r;
        red[wid][rl][0] = s1[mf * 4 + r];
        red[wid][rl][1] = s2[mf * 4 + r];
      }
  }
  __syncthreads();
  if (tid < 32) {
    float S1 = 0.f, S2 = 0.f;
    #pragma unroll
    for (int w = 0; w < 8; ++w) { S1 += red[w][tid][0]; S2 += red[w][tid][1]; }
    float mean = S1 * (1.0f / 768.0f);
    float var = S2 * (1.0f / 768.0f) - mean * mean;
    rowstat[tid][0] = mean;
    rowstat[tid][1] = rsqrtf(var + 1e-5f);
  }
  __syncthreads();

  float gm[6], bt[6];
  #pragma unroll
  for (int nf = 0; nf < 6; ++nf) {
    gm[nf] = gamma[cbase + nf * 16 + l15];
    bt[nf] = beta[cbase + nf * 16 + l15];
  }
  #pragma unroll
  for (int mf = 0; mf < 2; ++mf) {
    #pragma unroll
    for (int r = 0; r < 4; ++r) {
      const int rl = mf * 16 + g * 4 + r;
      const int m = blk * 32 + rl;
      const int bb = m / 196;
      const int orow = bb * 197 + 1 + (m - bb * 196);
      const float mean = rowstat[rl][0], rstd = rowstat[rl][1];
      float* op = out + (size_t)orow * DTOK + cbase + l15;
      #pragma unroll
      for (int nf = 0; nf < 6; ++nf)
        op[nf * 16] = (acc[mf][nf][r] - mean) * rstd * gm[nf] + bt[nf];
    }
  }
}

extern "C" void kernel_launch(void* const* d_in, const int* in_sizes, int n_in,
                              void* d_out, int out_size, void* d_ws, size_t ws_size,
                              hipStream_t stream) {
  const float* images = (const float*)d_in[0];
  const float* W      = (const float*)d_in[1];
  const float* bias   = (const float*)d_in[2];
  const float* cls    = (const float*)d_in[3];
  const float* gamma  = (const float*)d_in[4];
  const float* beta   = (const float*)d_in[5];
  float* out = (float*)d_out;

  unsigned short* Wb = (unsigned short*)d_ws;                       // 768*768*2 B
  float* bpos = (float*)((char*)d_ws + (size_t)DTOK * DTOK * 2);    // 197*768*4 B

  conv_w<<<(DTOK * DTOK + 255) / 256, 256, 0, stream>>>(W, Wb);
  make_bpos<<<(NTOK * DTOK + 255) / 256, 256, 0, stream>>>(bias, cls, bpos);
  cls_kernel<<<1, 256, 0, stream>>>(bpos, gamma, beta, out);
  vit_main<<<MROWS / 32, 512, 0, stream>>>(images, Wb, bpos, gamma, beta, out);
}